// Round 7
// baseline (536.841 us; speedup 1.0000x reference)
//
#include <hip/hip_runtime.h>

// ---------------------------------------------------------------------------
// BasicTransformerBlock on MI355X (gfx950).
// R7: barrier-free register-direct GEMM. The LDS+syncthreads K-loop is phase-
// locked (every barrier drains vmcnt(0) -> ~16% MfmaUtil plateau, R2-R6).
// Now each wave computes an independent 64x64 (GEGLU: 64x32 dual) tile,
// loading MFMA fragments straight from global/L2 (BK=64 groups = full 128B
// lines), zero LDS, zero barriers -> compiler emits fine-grained vmcnt(N).
// All GEMM buffer strides padded +8 halves to break pow-2 row strides.
// gelu via tanh/exp2 (~3x cheaper than erff). Attention unchanged (R4 form).
// ---------------------------------------------------------------------------

typedef _Float16 half8 __attribute__((ext_vector_type(8)));
typedef float f32x4 __attribute__((ext_vector_type(4)));

__device__ __forceinline__ f32x4 mfma16(half8 a, half8 b, f32x4 c) {
  return __builtin_amdgcn_mfma_f32_16x16x32_f16(a, b, c, 0, 0, 0);
}

__device__ __forceinline__ void gload16(const _Float16* g, _Float16* l) {
  __builtin_amdgcn_global_load_lds(
      (const __attribute__((address_space(1))) void*)g,
      (__attribute__((address_space(3))) void*)l, 16, 0, 0);
}

// ---------------- fused weight prep: 10 transposes + enc convert -----------
struct PrepArgs {
  const float* src[10];
  _Float16* dst[10];
  int K[10], N[10], base[10], ldT[10];
  const float* enc;
  _Float16* ench;
  int encBase, nEnc;
};

__global__ __launch_bounds__(256)
void prep_all(PrepArgs pa) {
  __shared__ float tile[32][33];
  const int bid = blockIdx.x;
  const int tx = threadIdx.x, ty = threadIdx.y;
  if (bid >= pa.encBase) {
    const int i = (bid - pa.encBase) * 256 + ty * 32 + tx;
    if (i < pa.nEnc) pa.ench[i] = (_Float16)pa.enc[i];
    return;
  }
  int mi = 0;
  #pragma unroll
  for (int j = 1; j < 10; j++)
    if (bid >= pa.base[j]) mi = j;
  const int N = pa.N[mi], ldT = pa.ldT[mi];
  const int rel = bid - pa.base[mi];
  const int ntiles = N >> 5;
  const int bx = rel % ntiles, by = rel / ntiles;
  const float* src = pa.src[mi];
  _Float16* dst = pa.dst[mi];
  const int n0 = bx * 32, k0 = by * 32;
  #pragma unroll
  for (int j = ty; j < 32; j += 8)
    tile[j][tx] = src[(size_t)(k0 + j) * N + n0 + tx];
  __syncthreads();
  #pragma unroll
  for (int j = ty; j < 32; j += 8)
    dst[(size_t)(n0 + j) * ldT + k0 + tx] = (_Float16)tile[tx][j];
}

// ---------------- V transpose: [b*S+s][h*64+d] -> [(bh*64)+d][s] -----------
__global__ __launch_bounds__(256)
void vt_kernel(const _Float16* __restrict__ src, _Float16* __restrict__ dst,
               int S, int srcStride, int dstStride) {
  __shared__ _Float16 tile[32][33];
  const int tx = threadIdx.x, ty = threadIdx.y;  // (32,8)
  const int s0 = blockIdx.x * 32, d0 = blockIdx.y * 32, bh = blockIdx.z;
  const int b = bh >> 3, h = bh & 7;
  const _Float16* sp = src + (size_t)b * S * srcStride + h * 64 + d0;
  #pragma unroll
  for (int j = ty; j < 32; j += 8) {
    int s = s0 + j; if (s >= S) s = S - 1;
    tile[j][tx] = sp[(size_t)s * srcStride + tx];
  }
  __syncthreads();
  _Float16* dp = dst + ((size_t)bh * 64 + d0) * dstStride + s0;
  #pragma unroll
  for (int j = ty; j < 32; j += 8)
    dp[(size_t)j * dstStride + tx] = tile[tx][j];
}

// ---------------- LayerNorm (row=512), fp32 in -> f16 out (ld-out) ---------
__global__ __launch_bounds__(256)
void ln_kernel(const float* __restrict__ x, const float* __restrict__ g,
               const float* __restrict__ b, _Float16* __restrict__ out,
               int ldo) {
  const int row = blockIdx.x, t = threadIdx.x;
  const float* xr = x + (size_t)row * 512;
  float v0 = xr[t], v1 = xr[t + 256];
  float s1 = v0 + v1, s2 = v0 * v0 + v1 * v1;
  #pragma unroll
  for (int m = 32; m >= 1; m >>= 1) {
    s1 += __shfl_xor(s1, m);
    s2 += __shfl_xor(s2, m);
  }
  __shared__ float red[8];
  if ((t & 63) == 0) { red[t >> 6] = s1; red[4 + (t >> 6)] = s2; }
  __syncthreads();
  s1 = red[0] + red[1] + red[2] + red[3];
  s2 = red[4] + red[5] + red[6] + red[7];
  const float mu = s1 * (1.0f / 512.0f);
  const float var = s2 * (1.0f / 512.0f) - mu * mu;
  const float rs = rsqrtf(var + 1e-5f);
  out[(size_t)row * ldo + t] = (_Float16)((v0 - mu) * rs * g[t] + b[t]);
  out[(size_t)row * ldo + t + 256] =
      (_Float16)((v1 - mu) * rs * g[t + 256] + b[t + 256]);
}

// ---------------- barrier-free wave GEMM -----------------------------------
// One wave computes (WM*16) x (WN*16) of C = A[M,K] @ BT[N,K]^T. Fragments
// load direct from global (BK=64 groups -> full 128B lines per row). No LDS,
// no __syncthreads -> compiler interleaves MFMA with loads via vmcnt(N).
// wid m-inner so a block's 4 waves share the same B rows (L1/L2 reuse).
// EPI 0: f16 -> Ch(ldc). EPI 1: Cf = resid + acc + bias (f32, ld 512).
// EPI 2: GEGLU dual-acc; g rows at BT + dualOff*ldb; Ch = u * gelu_tanh(g).
template <int EPI, int WM, int WN, int MW>
__global__ __launch_bounds__(256, MW)
void gemm_wave(const _Float16* __restrict__ A, const _Float16* __restrict__ BT,
               int M, int NMT, int K, int lda, int ldb, int ldc,
               _Float16* __restrict__ Ch, float* __restrict__ Cf,
               const float* __restrict__ bias, const float* __restrict__ resid,
               int dualOff) {
  const int t = threadIdx.x;
  const int lane = t & 63, quad = lane >> 4, l15 = lane & 15;
  const int wid = blockIdx.x * 4 + (t >> 6);
  const int bm = wid % NMT, bn = wid / NMT;
  const int m0 = bm * (WM * 16), n0 = bn * (WN * 16);

  f32x4 zero4 = {0.f, 0.f, 0.f, 0.f};
  f32x4 acc[WM][WN];
  f32x4 acc2[(EPI == 2) ? WM : 1][(EPI == 2) ? WN : 1];
  #pragma unroll
  for (int mi = 0; mi < WM; mi++)
    #pragma unroll
    for (int ni = 0; ni < WN; ni++) acc[mi][ni] = zero4;
  if constexpr (EPI == 2) {
    #pragma unroll
    for (int mi = 0; mi < WM; mi++)
      #pragma unroll
      for (int ni = 0; ni < WN; ni++) acc2[mi][ni] = zero4;
  }

  const _Float16* ap[WM];
  #pragma unroll
  for (int mi = 0; mi < WM; mi++) {
    int r = m0 + mi * 16 + l15; if (r >= M) r = M - 1;
    ap[mi] = A + (size_t)r * lda + quad * 8;
  }
  const _Float16* bp[WN];
  const _Float16* b2p[(EPI == 2) ? WN : 1];
  #pragma unroll
  for (int ni = 0; ni < WN; ni++) {
    bp[ni] = BT + (size_t)(n0 + ni * 16 + l15) * ldb + quad * 8;
    if constexpr (EPI == 2)
      b2p[ni] = BT + (size_t)(dualOff + n0 + ni * 16 + l15) * ldb + quad * 8;
  }

  #pragma unroll 2
  for (int k0 = 0; k0 < K; k0 += 64) {
    half8 av[2][WM], bv[2][WN], b2v[2][(EPI == 2) ? WN : 1];
    #pragma unroll
    for (int kk = 0; kk < 2; kk++) {
      #pragma unroll
      for (int mi = 0; mi < WM; mi++)
        av[kk][mi] = *(const half8*)(ap[mi] + k0 + kk * 32);
      #pragma unroll
      for (int ni = 0; ni < WN; ni++) {
        bv[kk][ni] = *(const half8*)(bp[ni] + k0 + kk * 32);
        if constexpr (EPI == 2)
          b2v[kk][ni] = *(const half8*)(b2p[ni] + k0 + kk * 32);
      }
    }
    #pragma unroll
    for (int kk = 0; kk < 2; kk++)
      #pragma unroll
      for (int mi = 0; mi < WM; mi++)
        #pragma unroll
        for (int ni = 0; ni < WN; ni++) {
          acc[mi][ni] = mfma16(av[kk][mi], bv[kk][ni], acc[mi][ni]);
          if constexpr (EPI == 2)
            acc2[mi][ni] = mfma16(av[kk][mi], b2v[kk][ni], acc2[mi][ni]);
        }
  }

  // epilogue: D row = quad*4 + r, col = l15 (verified C/D layout)
  #pragma unroll
  for (int mi = 0; mi < WM; mi++) {
    const int rbase = m0 + mi * 16 + quad * 4;
    #pragma unroll
    for (int r = 0; r < 4; r++) {
      const int row = rbase + r;
      if (row >= M) continue;
      #pragma unroll
      for (int ni = 0; ni < WN; ni++) {
        const int col = n0 + ni * 16 + l15;
        const float v = acc[mi][ni][r];
        if constexpr (EPI == 0) {
          Ch[(size_t)row * ldc + col] = (_Float16)v;
        } else if constexpr (EPI == 1) {
          Cf[(size_t)row * 512 + col] =
              resid[(size_t)row * 512 + col] + v + bias[col];
        } else {
          const float u = v + bias[col];
          const float gg = acc2[mi][ni][r] + bias[col + dualOff];
          // tanh-gelu via exp2 (max err ~1e-3, threshold 0.1)
          const float y = 0.7978845608f * (gg + 0.044715f * gg * gg * gg);
          const float e = exp2f(2.885390082f * y);
          const float th = (e - 1.0f) / (e + 1.0f);
          Ch[(size_t)row * ldc + col] = (_Float16)(u * 0.5f * gg * (1.0f + th));
        }
      }
    }
  }
}

// ---------------- flash attention (R4/R5 form, strides parametrized) -------
__global__ __launch_bounds__(256)
void attn2(const _Float16* __restrict__ Q, const _Float16* __restrict__ K,
           const _Float16* __restrict__ VT, _Float16* __restrict__ O,
           int qStride, int kStride, long kBatchStride,
           int vtStride, int Sk, int ldO) {
  __shared__ __align__(16) _Float16 KsL[2][2048];
  __shared__ __align__(16) _Float16 VTsL[2][2048];
  __shared__ __align__(16) _Float16 Ps[4][2][16][40];

  const int t = threadIdx.x;
  const int w = t >> 6, lane = t & 63, quad = lane >> 4, l15 = lane & 15;
  const int bh = blockIdx.y, b = bh >> 3, h = bh & 7;
  const int q0 = blockIdx.x * 128 + w * 32;

  const _Float16 qscale = (_Float16)(0.125f * 1.44269504f);
  half8 qf[2][2];
  #pragma unroll
  for (int mi = 0; mi < 2; mi++)
    #pragma unroll
    for (int c = 0; c < 2; c++) {
      const _Float16* qp = Q +
          (size_t)(b * 1024 + q0 + mi * 16 + l15) * qStride +
          h * 64 + c * 32 + quad * 8;
      half8 v = *(const half8*)qp;
      #pragma unroll
      for (int j = 0; j < 8; j++) v[j] *= qscale;
      qf[mi][c] = v;
    }

  f32x4 zero4 = {0.f, 0.f, 0.f, 0.f};
  f32x4 oa[2][4];
  float psum[2][4];
  #pragma unroll
  for (int mi = 0; mi < 2; mi++) {
    #pragma unroll
    for (int nt = 0; nt < 4; nt++) oa[mi][nt] = zero4;
    #pragma unroll
    for (int r = 0; r < 4; r++) psum[mi][r] = 0.f;
  }

  const _Float16* kp = K + (size_t)b * kBatchStride + h * 64;
  const _Float16* vtp = VT + (size_t)bh * 64 * vtStride;
  const int ksk = t & 31, kc = t >> 7, kqd = (t >> 5) & 3;
  const int vd = t & 63, vqd = t >> 6;

  auto stageKV = [&](int skb, int pb) {
    int skc = skb + ksk; if (skc >= Sk) skc = Sk - 1;
    gload16(kp + (size_t)skc * kStride + kc * 32 + kqd * 8, &KsL[pb][t * 8]);
    gload16(vtp + (size_t)vd * vtStride + skb + vqd * 8, &VTsL[pb][t * 8]);
  };

  stageKV(0, 0);
  __syncthreads();

  int it = 0;
  for (int skb = 0; skb < Sk; skb += 32, ++it) {
    const int cur = it & 1;
    if (skb + 32 < Sk) stageKV(skb + 32, cur ^ 1);

    const bool tail = (skb + 32 > Sk);
    #pragma unroll
    for (int mi = 0; mi < 2; mi++) {
      #pragma unroll
      for (int ct = 0; ct < 2; ct++) {
        f32x4 s = zero4;
        half8 kb0 = *(const half8*)(&KsL[cur][(quad * 32 + ct * 16 + l15) * 8]);
        half8 kb1 =
            *(const half8*)(&KsL[cur][(128 + quad * 32 + ct * 16 + l15) * 8]);
        s = mfma16(qf[mi][0], kb0, s);
        s = mfma16(qf[mi][1], kb1, s);
        if (tail) {
          const bool valid = (skb + ct * 16 + l15) < Sk;
          #pragma unroll
          for (int r = 0; r < 4; r++)
            if (!valid) s[r] = -__builtin_inff();
        }
        #pragma unroll
        for (int r = 0; r < 4; r++) {
          const float e = exp2f(s[r]);
          psum[mi][r] += e;
          Ps[w][mi][quad * 4 + r][ct * 16 + l15] = (_Float16)e;
        }
      }
    }
    #pragma unroll
    for (int mi = 0; mi < 2; mi++) {
      const half8 pf = *(const half8*)(&Ps[w][mi][l15][quad * 8]);
      #pragma unroll
      for (int nt = 0; nt < 4; nt++) {
        const half8 vf =
            *(const half8*)(&VTsL[cur][(quad * 64 + nt * 16 + l15) * 8]);
        oa[mi][nt] = mfma16(pf, vf, oa[mi][nt]);
      }
    }
    __syncthreads();
  }

  #pragma unroll
  for (int mi = 0; mi < 2; mi++)
    #pragma unroll
    for (int r = 0; r < 4; r++) {
      #pragma unroll
      for (int mm = 1; mm < 16; mm <<= 1)
        psum[mi][r] += __shfl_xor(psum[mi][r], mm);
      psum[mi][r] = 1.0f / psum[mi][r];
    }

  #pragma unroll
  for (int mi = 0; mi < 2; mi++)
    #pragma unroll
    for (int nt = 0; nt < 4; nt++)
      #pragma unroll
      for (int r = 0; r < 4; r++) {
        const size_t row = (size_t)(b * 1024 + q0 + mi * 16 + quad * 4 + r);
        O[row * ldO + h * 64 + nt * 16 + l15] =
            (_Float16)(oa[mi][nt][r] * psum[mi][r]);
      }
}

// ---------------------------------------------------------------------------
extern "C" void kernel_launch(void* const* d_in, const int* in_sizes, int n_in,
                              void* d_out, int out_size, void* d_ws,
                              size_t ws_size, hipStream_t stream) {
  const float* x    = (const float*)d_in[0];
  const float* enc  = (const float*)d_in[1];
  const float* ln1g = (const float*)d_in[2];
  const float* ln1b = (const float*)d_in[3];
  const float* wq1  = (const float*)d_in[4];
  const float* wk1  = (const float*)d_in[5];
  const float* wv1  = (const float*)d_in[6];
  const float* wo1  = (const float*)d_in[7];
  const float* bo1  = (const float*)d_in[8];
  const float* ln2g = (const float*)d_in[9];
  const float* ln2b = (const float*)d_in[10];
  const float* wq2  = (const float*)d_in[11];
  const float* wk2  = (const float*)d_in[12];
  const float* wv2  = (const float*)d_in[13];
  const float* wo2  = (const float*)d_in[14];
  const float* bo2  = (const float*)d_in[15];
  const float* ln3g = (const float*)d_in[16];
  const float* ln3b = (const float*)d_in[17];
  const float* wg   = (const float*)d_in[18];
  const float* bg   = (const float*)d_in[19];
  const float* wf   = (const float*)d_in[20];
  const float* bfp  = (const float*)d_in[21];
  float* out = (float*)d_out;

  char* ws = (char*)d_ws;
  // arena (padded strides: weights K+8; activations 520/2056)
  _Float16* qkvT  = (_Float16*)(ws + 0);          // [1536,520]
  _Float16* q2T   = (_Float16*)(ws + 1601536);    // [512,520]
  _Float16* kv2T  = (_Float16*)(ws + 2138112);    // [1024,776]
  _Float16* wo1T  = (_Float16*)(ws + 3731456);    // [512,520]
  _Float16* wo2T  = (_Float16*)(ws + 4268032);    // [512,520]
  _Float16* wgT   = (_Float16*)(ws + 4804608);    // [4096,520]
  _Float16* wfT   = (_Float16*)(ws + 9068544);    // [512,2056]
  _Float16* hbuf  = (_Float16*)(ws + 11177984);   // [8192,520]
  _Float16* qkv   = (_Float16*)(ws + 19701760);   // [8192,1536]
  _Float16* q2b   = (_Float16*)(ws + 44871680);   // [8192,520]
  _Float16* kv2b  = (_Float16*)(ws + 53395456);   // [616,1024]
  _Float16* attnb = (_Float16*)(ws + 54661120);   // [8192,520] ends 63.2MB
  _Float16* ench  = q2b;                          // [616,768] dead before q2
  _Float16* ffb   = (_Float16*)(ws + 19701760);   // [8192,2056] aliases qkv+
  _Float16* VTself = hbuf;                        // [4096,1024] (hbuf dead)
  _Float16* VTc    = kv2T;                        // [4096,96] (kv2T dead)

  // ---- fused weight prep (one launch) ----
  PrepArgs pa;
  const float* srcs[10] = {wq1, wk1, wv1, wo1, wq2, wk2, wv2, wo2, wg, wf};
  _Float16* dsts[10] = {qkvT, qkvT + 512 * 520, qkvT + 1024 * 520, wo1T, q2T,
                        kv2T, kv2T + 512 * 776, wo2T, wgT, wfT};
  const int Ks[10] = {512, 512, 512, 512, 512, 768, 768, 512, 512, 2048};
  const int Ns[10] = {512, 512, 512, 512, 512, 512, 512, 512, 4096, 512};
  int base = 0;
  for (int i = 0; i < 10; i++) {
    pa.src[i] = srcs[i]; pa.dst[i] = dsts[i];
    pa.K[i] = Ks[i]; pa.N[i] = Ns[i]; pa.base[i] = base;
    pa.ldT[i] = Ks[i] + 8;
    base += (Ks[i] >> 5) * (Ns[i] >> 5);
  }
  pa.enc = enc; pa.ench = ench; pa.encBase = base; pa.nEnc = 473088;
  const int prepBlocks = base + (473088 + 255) / 256;
  prep_all<<<prepBlocks, dim3(32, 8), 0, stream>>>(pa);

  const dim3 tb(32, 8);

  // ---- self-attention block ----
  ln_kernel<<<8192, 256, 0, stream>>>(x, ln1g, ln1b, hbuf, 520);
  gemm_wave<0, 4, 4, 3><<<768, 256, 0, stream>>>(          // QKV: 3072 waves
      hbuf, qkvT, 8192, 128, 512, 520, 520, 1536, qkv, nullptr, nullptr,
      nullptr, 0);
  vt_kernel<<<dim3(32, 2, 64), tb, 0, stream>>>(qkv + 1024, VTself, 1024,
                                                1536, 1024);
  attn2<<<dim3(8, 64), 256, 0, stream>>>(qkv, qkv + 512, VTself, attnb,
                                         1536, 1536, (long)1024 * 1536,
                                         1024, 1024, 520);
  gemm_wave<1, 4, 4, 3><<<256, 256, 0, stream>>>(          // oproj1
      attnb, wo1T, 8192, 128, 512, 520, 520, 512, nullptr, out, bo1, x, 0);

  // ---- cross-attention block (kv2 before q2: q2b aliases ench) ----
  ln_kernel<<<8192, 256, 0, stream>>>(out, ln2g, ln2b, hbuf, 520);
  gemm_wave<0, 4, 4, 3><<<40, 256, 0, stream>>>(           // kv2: 160 waves
      ench, kv2T, 616, 10, 768, 768, 776, 1024, kv2b, nullptr, nullptr,
      nullptr, 0);
  gemm_wave<0, 4, 4, 3><<<256, 256, 0, stream>>>(          // q2
      hbuf, q2T, 8192, 128, 512, 520, 520, 520, q2b, nullptr, nullptr,
      nullptr, 0);
  vt_kernel<<<dim3(3, 2, 64), tb, 0, stream>>>(kv2b + 512, VTc, 77, 1024, 96);
  attn2<<<dim3(8, 64), 256, 0, stream>>>(q2b, kv2b, VTc, attnb,
                                         520, 1024, (long)77 * 1024, 96, 77,
                                         520);
  gemm_wave<1, 4, 4, 3><<<256, 256, 0, stream>>>(          // oproj2
      attnb, wo2T, 8192, 128, 512, 520, 520, 512, nullptr, out, bo2, out, 0);

  // ---- GEGLU feed-forward ----
  ln_kernel<<<8192, 256, 0, stream>>>(out, ln3g, ln3b, hbuf, 520);
  gemm_wave<2, 4, 2, 3><<<2048, 256, 0, stream>>>(         // GEGLU: 8192 waves
      hbuf, wgT, 8192, 128, 512, 520, 520, 2056, ffb, nullptr, bg, nullptr,
      2048);
  gemm_wave<1, 4, 4, 3><<<256, 256, 0, stream>>>(          // FF2
      ffb, wfT, 8192, 128, 2048, 2056, 2056, 512, nullptr, out, bfp, out, 0);
}

// Round 8
// 499.250 us; speedup vs baseline: 1.0753x; 1.0753x over previous
//
#include <hip/hip_runtime.h>

// ---------------------------------------------------------------------------
// BasicTransformerBlock on MI355X (gfx950).
// R8: GEMMs are staging-BW-bound (FLOP per staged byte vs ~56 B/cyc/CU L2).
// GEGLU's dual-acc (64 FLOP/B) replaced by COLUMN-INTERLEAVED wgT (u/g pairs
// in adjacent columns) -> plain 128x128 GEMM (128 FLOP/B, single 64-reg acc),
// pairing via one __shfl_xor(1) in the epilogue. FF2/oproj/q2 upgraded from
// 64x128 (85 FLOP/B) to 128x128 (128 FLOP/B). R7's direct-load GEMM reverted
// (falsified: no LDS reuse -> 2x L2 traffic, MfmaUtil 12%). Structure = R6:
// global_load_lds dbuf, conflict-free fragment-major LDS, XCD swizzle,
// fused prep. erff gelu restored (absmax margin).
// ---------------------------------------------------------------------------

typedef _Float16 half8 __attribute__((ext_vector_type(8)));
typedef float f32x4 __attribute__((ext_vector_type(4)));

__device__ __forceinline__ f32x4 mfma16(half8 a, half8 b, f32x4 c) {
  return __builtin_amdgcn_mfma_f32_16x16x32_f16(a, b, c, 0, 0, 0);
}

__device__ __forceinline__ void gload16(const _Float16* g, _Float16* l) {
  __builtin_amdgcn_global_load_lds(
      (const __attribute__((address_space(1))) void*)g,
      (__attribute__((address_space(3))) void*)l, 16, 0, 0);
}

// ---------------- fused weight prep: 10 transposes + enc convert -----------
// perm flag (wg): dst row n -> (n<2048) ? 2n : 2(n-2048)+1  (u/g interleave)
struct PrepArgs {
  const float* src[10];
  _Float16* dst[10];
  int K[10], N[10], base[10], perm[10];
  const float* enc;
  _Float16* ench;
  int encBase, nEnc;
};

__global__ __launch_bounds__(256)
void prep_all(PrepArgs pa) {
  __shared__ float tile[32][33];
  const int bid = blockIdx.x;
  const int tx = threadIdx.x, ty = threadIdx.y;
  if (bid >= pa.encBase) {
    const int i = (bid - pa.encBase) * 256 + ty * 32 + tx;
    if (i < pa.nEnc) pa.ench[i] = (_Float16)pa.enc[i];
    return;
  }
  int mi = 0;
  #pragma unroll
  for (int j = 1; j < 10; j++)
    if (bid >= pa.base[j]) mi = j;
  const int K = pa.K[mi], N = pa.N[mi], pm = pa.perm[mi];
  const int rel = bid - pa.base[mi];
  const int ntiles = N >> 5;
  const int bx = rel % ntiles, by = rel / ntiles;
  const float* src = pa.src[mi];
  _Float16* dst = pa.dst[mi];
  const int n0 = bx * 32, k0 = by * 32;
  #pragma unroll
  for (int j = ty; j < 32; j += 8)
    tile[j][tx] = src[(size_t)(k0 + j) * N + n0 + tx];
  __syncthreads();
  #pragma unroll
  for (int j = ty; j < 32; j += 8) {
    int row = n0 + j;
    if (pm) row = (row < 2048) ? (row * 2) : ((row - 2048) * 2 + 1);
    dst[(size_t)row * K + k0 + tx] = (_Float16)tile[tx][j];
  }
}

// ---------------- V transpose: [b*S+s][h*64+d] -> [(bh*64)+d][s] -----------
__global__ __launch_bounds__(256)
void vt_kernel(const _Float16* __restrict__ src, _Float16* __restrict__ dst,
               int S, int srcStride, int dstStride) {
  __shared__ _Float16 tile[32][33];
  const int tx = threadIdx.x, ty = threadIdx.y;  // (32,8)
  const int s0 = blockIdx.x * 32, d0 = blockIdx.y * 32, bh = blockIdx.z;
  const int b = bh >> 3, h = bh & 7;
  const _Float16* sp = src + (size_t)b * S * srcStride + h * 64 + d0;
  #pragma unroll
  for (int j = ty; j < 32; j += 8) {
    int s = s0 + j; if (s >= S) s = S - 1;
    tile[j][tx] = sp[(size_t)s * srcStride + tx];
  }
  __syncthreads();
  _Float16* dp = dst + ((size_t)bh * 64 + d0) * dstStride + s0;
  #pragma unroll
  for (int j = ty; j < 32; j += 8)
    dp[(size_t)j * dstStride + tx] = tile[tx][j];
}

// ---------------- LayerNorm (row=512), fp32 in -> f16 out ------------------
__global__ __launch_bounds__(256)
void ln_kernel(const float* __restrict__ x, const float* __restrict__ g,
               const float* __restrict__ b, _Float16* __restrict__ out) {
  const int row = blockIdx.x, t = threadIdx.x;
  const float* xr = x + (size_t)row * 512;
  float v0 = xr[t], v1 = xr[t + 256];
  float s1 = v0 + v1, s2 = v0 * v0 + v1 * v1;
  #pragma unroll
  for (int m = 32; m >= 1; m >>= 1) {
    s1 += __shfl_xor(s1, m);
    s2 += __shfl_xor(s2, m);
  }
  __shared__ float red[8];
  if ((t & 63) == 0) { red[t >> 6] = s1; red[4 + (t >> 6)] = s2; }
  __syncthreads();
  s1 = red[0] + red[1] + red[2] + red[3];
  s2 = red[4] + red[5] + red[6] + red[7];
  const float mu = s1 * (1.0f / 512.0f);
  const float var = s2 * (1.0f / 512.0f) - mu * mu;
  const float rs = rsqrtf(var + 1e-5f);
  out[(size_t)row * 512 + t] = (_Float16)((v0 - mu) * rs * g[t] + b[t]);
  out[(size_t)row * 512 + t + 256] =
      (_Float16)((v1 - mu) * rs * g[t + 256] + b[t + 256]);
}

// ---------------- GEMM: C = A[M,K] @ BT[N,K]^T, dbuf + XCD swizzle ---------
// EPI 0: f16 store. EPI 1: Cf = resid + acc + bias (f32). EPI 3: GEGLU-paired
// (BT rows pre-interleaved u/g): partner via __shfl_xor(1); even lanes store
// u*gelu(g) to col>>1.
template <int EPI, int GWM, int GWN, int WM, int WN, int MW, int SWZ>
__global__ __launch_bounds__(256, MW)
void gemm_bt(const _Float16* __restrict__ A, const _Float16* __restrict__ BT,
             int M, int N, int K, int lda, int ldc,
             _Float16* Ch, float* Cf,
             const float* __restrict__ bias, const float* resid) {
  constexpr int BM = GWM * WM * 16;
  constexpr int BN = GWN * WN * 16;
  __shared__ __align__(16) _Float16 As[2][4 * BM * 8];
  __shared__ __align__(16) _Float16 Bs[2][4 * BN * 8];

  const int t = threadIdx.x;
  const int NNB = (N + BN - 1) / BN;
  int bm, bn;
  if constexpr (SWZ) {
    const int MG = (M / BM) >> 3;
    const int xcd = blockIdx.x & 7;
    const int s = blockIdx.x >> 3;
    bm = xcd * MG + s % MG;
    bn = s / MG;
  } else {
    bn = blockIdx.x % NNB;
    bm = blockIdx.x / NNB;
  }
  const int m0 = bm * BM, n0 = bn * BN;
  const int lane = t & 63, wv = t >> 6;
  const int quad = lane >> 4, l15 = lane & 15;
  const int wm = wv / GWN, wn = wv % GWN;

  f32x4 zero4 = {0.f, 0.f, 0.f, 0.f};
  f32x4 acc[WM][WN];
  #pragma unroll
  for (int mi = 0; mi < WM; mi++)
    #pragma unroll
    for (int ni = 0; ni < WN; ni++) acc[mi][ni] = zero4;

  auto stageAll = [&](int k0, int pb) {
    #pragma unroll
    for (int c = wv; c < BM / 16; c += 4) {
      const int s = c * 64 + lane;
      const int q = s / BM;
      const int r = s % BM;
      int rg = m0 + r; if (rg >= M) rg = M - 1;
      gload16(A + (size_t)rg * lda + k0 + q * 8, &As[pb][c * 512]);
    }
    #pragma unroll
    for (int c = wv; c < BN / 16; c += 4) {
      const int s = c * 64 + lane;
      const int q = s / BN;
      const int r = s % BN;
      gload16(BT + (size_t)(n0 + r) * K + k0 + q * 8, &Bs[pb][c * 512]);
    }
  };

  stageAll(0, 0);
  __syncthreads();

  const int NIT = K >> 5;
  for (int it = 0; it < NIT; ++it) {
    const int cur = it & 1;
    if (it + 1 < NIT) stageAll((it + 1) << 5, cur ^ 1);

    half8 fa[WM], fb[WN];
    #pragma unroll
    for (int mi = 0; mi < WM; mi++)
      fa[mi] = *(const half8*)(&As[cur]
          [((size_t)quad * BM + wm * WM * 16 + mi * 16 + l15) * 8]);
    #pragma unroll
    for (int ni = 0; ni < WN; ni++)
      fb[ni] = *(const half8*)(&Bs[cur]
          [((size_t)quad * BN + wn * WN * 16 + ni * 16 + l15) * 8]);
    #pragma unroll
    for (int mi = 0; mi < WM; mi++)
      #pragma unroll
      for (int ni = 0; ni < WN; ni++)
        acc[mi][ni] = mfma16(fa[mi], fb[ni], acc[mi][ni]);
    __syncthreads();
  }

  // epilogue: D row = quad*4 + r, col = l15 (verified C/D layout)
  #pragma unroll
  for (int mi = 0; mi < WM; mi++) {
    const int rbase = m0 + wm * WM * 16 + mi * 16 + quad * 4;
    #pragma unroll
    for (int r = 0; r < 4; r++) {
      const int row = rbase + r;
      #pragma unroll
      for (int ni = 0; ni < WN; ni++) {
        const int col = n0 + wn * WN * 16 + ni * 16 + l15;
        const float v = acc[mi][ni][r];
        if constexpr (EPI == 0) {
          if (row < M) Ch[(size_t)row * ldc + col] = (_Float16)v;
        } else if constexpr (EPI == 1) {
          if (row < M)
            Cf[(size_t)row * ldc + col] =
                resid[(size_t)row * ldc + col] + v + bias[col];
        } else {
          // paired GEGLU: even col=u, odd col=g (same pair index col>>1)
          const float vb = v + bias[(col >> 1) + ((col & 1) << 11)];
          const float other = __shfl_xor(vb, 1);
          if (!(col & 1) && row < M) {
            const float gg = other;
            const float ge = 0.5f * gg * (1.0f + erff(gg * 0.70710678118f));
            Ch[(size_t)row * ldc + (col >> 1)] = (_Float16)(vb * ge);
          }
        }
      }
    }
  }
}

// ---------------- flash attention v2, double-buffered (R6) -----------------
__global__ __launch_bounds__(256)
void attn2(const _Float16* __restrict__ Q, const _Float16* __restrict__ K,
           const _Float16* __restrict__ VT, _Float16* __restrict__ O,
           int qStride, int kStride, long kBatchStride,
           int vtStride, int Sk) {
  __shared__ __align__(16) _Float16 KsL[2][2048];
  __shared__ __align__(16) _Float16 VTsL[2][2048];
  __shared__ __align__(16) _Float16 Ps[4][2][16][40];

  const int t = threadIdx.x;
  const int w = t >> 6, lane = t & 63, quad = lane >> 4, l15 = lane & 15;
  const int bh = blockIdx.y, b = bh >> 3, h = bh & 7;
  const int q0 = blockIdx.x * 128 + w * 32;

  const _Float16 qscale = (_Float16)(0.125f * 1.44269504f);
  half8 qf[2][2];
  #pragma unroll
  for (int mi = 0; mi < 2; mi++)
    #pragma unroll
    for (int c = 0; c < 2; c++) {
      const _Float16* qp = Q +
          (size_t)(b * 1024 + q0 + mi * 16 + l15) * qStride +
          h * 64 + c * 32 + quad * 8;
      half8 v = *(const half8*)qp;
      #pragma unroll
      for (int j = 0; j < 8; j++) v[j] *= qscale;
      qf[mi][c] = v;
    }

  f32x4 zero4 = {0.f, 0.f, 0.f, 0.f};
  f32x4 oa[2][4];
  float psum[2][4];
  #pragma unroll
  for (int mi = 0; mi < 2; mi++) {
    #pragma unroll
    for (int nt = 0; nt < 4; nt++) oa[mi][nt] = zero4;
    #pragma unroll
    for (int r = 0; r < 4; r++) psum[mi][r] = 0.f;
  }

  const _Float16* kp = K + (size_t)b * kBatchStride + h * 64;
  const _Float16* vtp = VT + (size_t)bh * 64 * vtStride;
  const int ksk = t & 31, kc = t >> 7, kqd = (t >> 5) & 3;
  const int vd = t & 63, vqd = t >> 6;

  auto stageKV = [&](int skb, int pb) {
    int skc = skb + ksk; if (skc >= Sk) skc = Sk - 1;
    gload16(kp + (size_t)skc * kStride + kc * 32 + kqd * 8, &KsL[pb][t * 8]);
    gload16(vtp + (size_t)vd * vtStride + skb + vqd * 8, &VTsL[pb][t * 8]);
  };

  stageKV(0, 0);
  __syncthreads();

  int it = 0;
  for (int skb = 0; skb < Sk; skb += 32, ++it) {
    const int cur = it & 1;
    if (skb + 32 < Sk) stageKV(skb + 32, cur ^ 1);

    const bool tail = (skb + 32 > Sk);
    #pragma unroll
    for (int mi = 0; mi < 2; mi++) {
      #pragma unroll
      for (int ct = 0; ct < 2; ct++) {
        f32x4 s = zero4;
        half8 kb0 = *(const half8*)(&KsL[cur][(quad * 32 + ct * 16 + l15) * 8]);
        half8 kb1 =
            *(const half8*)(&KsL[cur][(128 + quad * 32 + ct * 16 + l15) * 8]);
        s = mfma16(qf[mi][0], kb0, s);
        s = mfma16(qf[mi][1], kb1, s);
        if (tail) {
          const bool valid = (skb + ct * 16 + l15) < Sk;
          #pragma unroll
          for (int r = 0; r < 4; r++)
            if (!valid) s[r] = -__builtin_inff();
        }
        #pragma unroll
        for (int r = 0; r < 4; r++) {
          const float e = exp2f(s[r]);
          psum[mi][r] += e;
          Ps[w][mi][quad * 4 + r][ct * 16 + l15] = (_Float16)e;
        }
      }
    }
    #pragma unroll
    for (int mi = 0; mi < 2; mi++) {
      const half8 pf = *(const half8*)(&Ps[w][mi][l15][quad * 8]);
      #pragma unroll
      for (int nt = 0; nt < 4; nt++) {
        const half8 vf =
            *(const half8*)(&VTsL[cur][(quad * 64 + nt * 16 + l15) * 8]);
        oa[mi][nt] = mfma16(pf, vf, oa[mi][nt]);
      }
    }
    __syncthreads();
  }

  #pragma unroll
  for (int mi = 0; mi < 2; mi++)
    #pragma unroll
    for (int r = 0; r < 4; r++) {
      #pragma unroll
      for (int mm = 1; mm < 16; mm <<= 1)
        psum[mi][r] += __shfl_xor(psum[mi][r], mm);
      psum[mi][r] = 1.0f / psum[mi][r];
    }

  #pragma unroll
  for (int mi = 0; mi < 2; mi++)
    #pragma unroll
    for (int nt = 0; nt < 4; nt++)
      #pragma unroll
      for (int r = 0; r < 4; r++) {
        const size_t row = (size_t)(b * 1024 + q0 + mi * 16 + quad * 4 + r);
        O[row * 512 + h * 64 + nt * 16 + l15] =
            (_Float16)(oa[mi][nt][r] * psum[mi][r]);
      }
}

// ---------------------------------------------------------------------------
extern "C" void kernel_launch(void* const* d_in, const int* in_sizes, int n_in,
                              void* d_out, int out_size, void* d_ws,
                              size_t ws_size, hipStream_t stream) {
  const float* x    = (const float*)d_in[0];
  const float* enc  = (const float*)d_in[1];
  const float* ln1g = (const float*)d_in[2];
  const float* ln1b = (const float*)d_in[3];
  const float* wq1  = (const float*)d_in[4];
  const float* wk1  = (const float*)d_in[5];
  const float* wv1  = (const float*)d_in[6];
  const float* wo1  = (const float*)d_in[7];
  const float* bo1  = (const float*)d_in[8];
  const float* ln2g = (const float*)d_in[9];
  const float* ln2b = (const float*)d_in[10];
  const float* wq2  = (const float*)d_in[11];
  const float* wk2  = (const float*)d_in[12];
  const float* wv2  = (const float*)d_in[13];
  const float* wo2  = (const float*)d_in[14];
  const float* bo2  = (const float*)d_in[15];
  const float* ln3g = (const float*)d_in[16];
  const float* ln3b = (const float*)d_in[17];
  const float* wg   = (const float*)d_in[18];
  const float* bg   = (const float*)d_in[19];
  const float* wf   = (const float*)d_in[20];
  const float* bfp  = (const float*)d_in[21];
  float* out = (float*)d_out;

  char* ws = (char*)d_ws;
  _Float16* qkvT  = (_Float16*)(ws + 0);         // [1536,512]
  _Float16* q2T   = (_Float16*)(ws + 1572864);   // [512,512]
  _Float16* kv2T  = (_Float16*)(ws + 2097152);   // [1024,768]
  _Float16* wo1T  = (_Float16*)(ws + 3670016);   // [512,512]
  _Float16* wo2T  = (_Float16*)(ws + 4194304);   // [512,512]
  _Float16* wgT   = (_Float16*)(ws + 4718592);   // [4096,512] (interleaved)
  _Float16* wfT   = (_Float16*)(ws + 8912896);   // [512,2048]
  _Float16* hbuf  = (_Float16*)(ws + 11010048);  // [8192,512] (VTself in attn1)
  _Float16* qkv   = (_Float16*)(ws + 19398656);  // [8192,1536]
  _Float16* q2b   = (_Float16*)(ws + 44564480);  // [8192,512]
  _Float16* kv2b  = (_Float16*)(ws + 52953088);  // [616,1024]
  _Float16* attnb = (_Float16*)(ws + 54214656);  // [8192,512]
  _Float16* ench  = (_Float16*)(ws + 62603264);  // [616,768]
  _Float16* ffb   = (_Float16*)(ws + 19398656);  // [8192,2048] aliases qkv+q2b
  _Float16* VTself = hbuf;                       // [4096,1024]
  _Float16* VTc    = kv2T;                       // reuse? no — kv2T needed; use ench region after
  VTc = (_Float16*)(ws + 62603264);              // [4096,96] over ench (dead)

  // ---- fused weight prep (one launch) ----
  PrepArgs pa;
  const float* srcs[10] = {wq1, wk1, wv1, wo1, wq2, wk2, wv2, wo2, wg, wf};
  _Float16* dsts[10] = {qkvT, qkvT + 512 * 512, qkvT + 1024 * 512, wo1T, q2T,
                        kv2T, kv2T + 512 * 768, wo2T, wgT, wfT};
  const int Ks[10] = {512, 512, 512, 512, 512, 768, 768, 512, 512, 2048};
  const int Ns[10] = {512, 512, 512, 512, 512, 512, 512, 512, 4096, 512};
  int base = 0;
  for (int i = 0; i < 10; i++) {
    pa.src[i] = srcs[i]; pa.dst[i] = dsts[i];
    pa.K[i] = Ks[i]; pa.N[i] = Ns[i]; pa.base[i] = base;
    pa.perm[i] = (i == 8) ? 1 : 0;
    base += (Ks[i] >> 5) * (Ns[i] >> 5);
  }
  // ench must be staged BEFORE attn VTc overwrites it -> it is consumed by
  // kv2 GEMM which runs before attn2-cross; VTc write happens after. OK.
  pa.enc = enc; pa.ench = ench; pa.encBase = base; pa.nEnc = 473088;
  const int prepBlocks = base + (473088 + 255) / 256;
  prep_all<<<prepBlocks, dim3(32, 8), 0, stream>>>(pa);

  const dim3 tb(32, 8);

  // ---- self-attention block ----
  ln_kernel<<<8192, 256, 0, stream>>>(x, ln1g, ln1b, hbuf);
  gemm_bt<0, 2, 2, 4, 4, 2, 1><<<768, 256, 0, stream>>>(
      hbuf, qkvT, 8192, 1536, 512, 512, 1536, qkv, nullptr, nullptr, nullptr);
  vt_kernel<<<dim3(32, 2, 64), tb, 0, stream>>>(qkv + 1024, VTself, 1024,
                                                1536, 1024);
  attn2<<<dim3(8, 64), 256, 0, stream>>>(qkv, qkv + 512, VTself, attnb,
                                         1536, 1536, (long)1024 * 1536,
                                         1024, 1024);
  gemm_bt<1, 2, 2, 4, 4, 2, 1><<<256, 256, 0, stream>>>(
      attnb, wo1T, 8192, 512, 512, 512, 512, nullptr, out, bo1, x);

  // ---- cross-attention block ----
  ln_kernel<<<8192, 256, 0, stream>>>(out, ln2g, ln2b, hbuf);
  gemm_bt<0, 2, 2, 4, 4, 2, 1><<<256, 256, 0, stream>>>(
      hbuf, q2T, 8192, 512, 512, 512, 512, q2b, nullptr, nullptr, nullptr);
  gemm_bt<0, 1, 4, 4, 2, 3, 0><<<80, 256, 0, stream>>>(
      ench, kv2T, 616, 1024, 768, 768, 1024, kv2b, nullptr, nullptr, nullptr);
  vt_kernel<<<dim3(3, 2, 64), tb, 0, stream>>>(kv2b + 512, VTc, 77, 1024, 96);
  attn2<<<dim3(8, 64), 256, 0, stream>>>(q2b, kv2b, VTc, attnb,
                                         512, 1024, (long)77 * 1024, 96, 77);
  gemm_bt<1, 2, 2, 4, 4, 2, 1><<<256, 256, 0, stream>>>(
      attnb, wo2T, 8192, 512, 512, 512, 512, nullptr, out, bo2, out);

  // ---- GEGLU feed-forward (interleaved single-acc) ----
  ln_kernel<<<8192, 256, 0, stream>>>(out, ln3g, ln3b, hbuf);
  gemm_bt<3, 2, 2, 4, 4, 2, 1><<<2048, 256, 0, stream>>>(
      hbuf, wgT, 8192, 4096, 512, 512, 2048, ffb, nullptr, bg, nullptr);
  gemm_bt<1, 2, 2, 4, 4, 2, 1><<<256, 256, 0, stream>>>(
      ffb, wfT, 8192, 512, 2048, 2048, 512, nullptr, out, bfp, out);
}

// Round 9
// 457.735 us; speedup vs baseline: 1.1728x; 1.0907x over previous
//
#include <hip/hip_runtime.h>

// ---------------------------------------------------------------------------
// BasicTransformerBlock on MI355X (gfx950).
// R9: revert to R6 configs (R8's 128x128-everywhere halved block counts of
// N=512 GEMMs -> lost cross-block latency hiding; interleave didn't change
// FLOP/B — arithmetic error). New: GEGLU MW=4 (120 regs <= 128 cap -> 4
// blocks/CU), QKV MW=3, LN1 folded into prep_all (one fewer dispatch).
// ---------------------------------------------------------------------------

typedef _Float16 half8 __attribute__((ext_vector_type(8)));
typedef float f32x4 __attribute__((ext_vector_type(4)));

__device__ __forceinline__ f32x4 mfma16(half8 a, half8 b, f32x4 c) {
  return __builtin_amdgcn_mfma_f32_16x16x32_f16(a, b, c, 0, 0, 0);
}

__device__ __forceinline__ void gload16(const _Float16* g, _Float16* l) {
  __builtin_amdgcn_global_load_lds(
      (const __attribute__((address_space(1))) void*)g,
      (__attribute__((address_space(3))) void*)l, 16, 0, 0);
}

// ---------------- fused prep: 10 weight transposes + enc cvt + LN1 ---------
struct PrepArgs {
  const float* src[10];
  _Float16* dst[10];
  int K[10], N[10], base[10];
  const float* enc;
  _Float16* ench;
  int encBase, nEnc;
  const float* x;
  const float* ln1g;
  const float* ln1b;
  _Float16* hbuf;
  int lnBase;  // first block index of LN rows (8192 rows follow)
};

__global__ __launch_bounds__(256)
void prep_all(PrepArgs pa) {
  __shared__ float tile[32][33];
  const int bid = blockIdx.x;
  const int tx = threadIdx.x, ty = threadIdx.y;
  const int t = ty * 32 + tx;
  if (bid >= pa.lnBase) {
    // -------- LayerNorm1 row --------
    const int row = bid - pa.lnBase;
    const float* xr = pa.x + (size_t)row * 512;
    float v0 = xr[t], v1 = xr[t + 256];
    float s1 = v0 + v1, s2 = v0 * v0 + v1 * v1;
    #pragma unroll
    for (int m = 32; m >= 1; m >>= 1) {
      s1 += __shfl_xor(s1, m);
      s2 += __shfl_xor(s2, m);
    }
    __shared__ float red[8];
    if ((t & 63) == 0) { red[t >> 6] = s1; red[4 + (t >> 6)] = s2; }
    __syncthreads();
    s1 = red[0] + red[1] + red[2] + red[3];
    s2 = red[4] + red[5] + red[6] + red[7];
    const float mu = s1 * (1.0f / 512.0f);
    const float var = s2 * (1.0f / 512.0f) - mu * mu;
    const float rs = rsqrtf(var + 1e-5f);
    pa.hbuf[(size_t)row * 512 + t] =
        (_Float16)((v0 - mu) * rs * pa.ln1g[t] + pa.ln1b[t]);
    pa.hbuf[(size_t)row * 512 + t + 256] =
        (_Float16)((v1 - mu) * rs * pa.ln1g[t + 256] + pa.ln1b[t + 256]);
    return;
  }
  if (bid >= pa.encBase) {
    const int i = (bid - pa.encBase) * 256 + t;
    if (i < pa.nEnc) pa.ench[i] = (_Float16)pa.enc[i];
    return;
  }
  int mi = 0;
  #pragma unroll
  for (int j = 1; j < 10; j++)
    if (bid >= pa.base[j]) mi = j;
  const int K = pa.K[mi], N = pa.N[mi];
  const int rel = bid - pa.base[mi];
  const int ntiles = N >> 5;
  const int bx = rel % ntiles, by = rel / ntiles;
  const float* src = pa.src[mi];
  _Float16* dst = pa.dst[mi];
  const int n0 = bx * 32, k0 = by * 32;
  #pragma unroll
  for (int j = ty; j < 32; j += 8)
    tile[j][tx] = src[(size_t)(k0 + j) * N + n0 + tx];
  __syncthreads();
  #pragma unroll
  for (int j = ty; j < 32; j += 8)
    dst[(size_t)(n0 + j) * K + k0 + tx] = (_Float16)tile[tx][j];
}

// ---------------- V transpose: [b*S+s][h*64+d] -> [(bh*64)+d][s] -----------
__global__ __launch_bounds__(256)
void vt_kernel(const _Float16* __restrict__ src, _Float16* __restrict__ dst,
               int S, int srcStride, int dstStride) {
  __shared__ _Float16 tile[32][33];
  const int tx = threadIdx.x, ty = threadIdx.y;  // (32,8)
  const int s0 = blockIdx.x * 32, d0 = blockIdx.y * 32, bh = blockIdx.z;
  const int b = bh >> 3, h = bh & 7;
  const _Float16* sp = src + (size_t)b * S * srcStride + h * 64 + d0;
  #pragma unroll
  for (int j = ty; j < 32; j += 8) {
    int s = s0 + j; if (s >= S) s = S - 1;
    tile[j][tx] = sp[(size_t)s * srcStride + tx];
  }
  __syncthreads();
  _Float16* dp = dst + ((size_t)bh * 64 + d0) * dstStride + s0;
  #pragma unroll
  for (int j = ty; j < 32; j += 8)
    dp[(size_t)j * dstStride + tx] = tile[tx][j];
}

// ---------------- LayerNorm (row=512), fp32 in -> f16 out ------------------
__global__ __launch_bounds__(256)
void ln_kernel(const float* __restrict__ x, const float* __restrict__ g,
               const float* __restrict__ b, _Float16* __restrict__ out) {
  const int row = blockIdx.x, t = threadIdx.x;
  const float* xr = x + (size_t)row * 512;
  float v0 = xr[t], v1 = xr[t + 256];
  float s1 = v0 + v1, s2 = v0 * v0 + v1 * v1;
  #pragma unroll
  for (int m = 32; m >= 1; m >>= 1) {
    s1 += __shfl_xor(s1, m);
    s2 += __shfl_xor(s2, m);
  }
  __shared__ float red[8];
  if ((t & 63) == 0) { red[t >> 6] = s1; red[4 + (t >> 6)] = s2; }
  __syncthreads();
  s1 = red[0] + red[1] + red[2] + red[3];
  s2 = red[4] + red[5] + red[6] + red[7];
  const float mu = s1 * (1.0f / 512.0f);
  const float var = s2 * (1.0f / 512.0f) - mu * mu;
  const float rs = rsqrtf(var + 1e-5f);
  out[(size_t)row * 512 + t] = (_Float16)((v0 - mu) * rs * g[t] + b[t]);
  out[(size_t)row * 512 + t + 256] =
      (_Float16)((v1 - mu) * rs * g[t + 256] + b[t + 256]);
}

// ---------------- GEMM: C = A[M,K] @ BT[N,K]^T, dbuf + XCD swizzle ---------
// EPI 0: f16 store. EPI 1: Cf = resid + acc + bias (f32). EPI 2: GEGLU dual.
template <int EPI, int GWM, int GWN, int WM, int WN, int MW, int SWZ>
__global__ __launch_bounds__(256, MW)
void gemm_bt(const _Float16* __restrict__ A, const _Float16* __restrict__ BT,
             int M, int N, int K, int lda, int ldc,
             _Float16* Ch, float* Cf,
             const float* __restrict__ bias, const float* resid) {
  constexpr int BM = GWM * WM * 16;
  constexpr int BN = GWN * WN * 16;
  __shared__ __align__(16) _Float16 As[2][4 * BM * 8];
  __shared__ __align__(16) _Float16 Bs[2][4 * BN * 8];
  __shared__ __align__(16) _Float16 Bs2[(EPI == 2) ? 2 : 1]
                                      [(EPI == 2) ? 4 * BN * 8 : 8];

  const int t = threadIdx.x;
  const int NNB = (N + BN - 1) / BN;
  int bm, bn;
  if constexpr (SWZ) {
    const int MG = (M / BM) >> 3;
    const int xcd = blockIdx.x & 7;
    const int s = blockIdx.x >> 3;
    bm = xcd * MG + s % MG;
    bn = s / MG;
  } else {
    bn = blockIdx.x % NNB;
    bm = blockIdx.x / NNB;
  }
  const int m0 = bm * BM, n0 = bn * BN;
  const int lane = t & 63, wv = t >> 6;
  const int quad = lane >> 4, l15 = lane & 15;
  const int wm = wv / GWN, wn = wv % GWN;

  f32x4 zero4 = {0.f, 0.f, 0.f, 0.f};
  f32x4 acc[WM][WN];
  f32x4 acc2[(EPI == 2) ? WM : 1][(EPI == 2) ? WN : 1];
  #pragma unroll
  for (int mi = 0; mi < WM; mi++)
    #pragma unroll
    for (int ni = 0; ni < WN; ni++) acc[mi][ni] = zero4;
  if constexpr (EPI == 2) {
    #pragma unroll
    for (int mi = 0; mi < WM; mi++)
      #pragma unroll
      for (int ni = 0; ni < WN; ni++) acc2[mi][ni] = zero4;
  }

  auto stageAll = [&](int k0, int pb) {
    #pragma unroll
    for (int c = wv; c < BM / 16; c += 4) {
      const int s = c * 64 + lane;
      const int q = s / BM;
      const int r = s % BM;
      int rg = m0 + r; if (rg >= M) rg = M - 1;
      gload16(A + (size_t)rg * lda + k0 + q * 8, &As[pb][c * 512]);
    }
    #pragma unroll
    for (int c = wv; c < BN / 16; c += 4) {
      const int s = c * 64 + lane;
      const int q = s / BN;
      const int r = s % BN;
      gload16(BT + (size_t)(n0 + r) * K + k0 + q * 8, &Bs[pb][c * 512]);
      if constexpr (EPI == 2)
        gload16(BT + (size_t)(2048 + n0 + r) * K + k0 + q * 8,
                &Bs2[pb][c * 512]);
    }
  };

  stageAll(0, 0);
  __syncthreads();

  const int NIT = K >> 5;
  for (int it = 0; it < NIT; ++it) {
    const int cur = it & 1;
    if (it + 1 < NIT) stageAll((it + 1) << 5, cur ^ 1);

    half8 fa[WM], fb[WN], fb2[(EPI == 2) ? WN : 1];
    #pragma unroll
    for (int mi = 0; mi < WM; mi++)
      fa[mi] = *(const half8*)(&As[cur]
          [((size_t)quad * BM + wm * WM * 16 + mi * 16 + l15) * 8]);
    #pragma unroll
    for (int ni = 0; ni < WN; ni++) {
      fb[ni] = *(const half8*)(&Bs[cur]
          [((size_t)quad * BN + wn * WN * 16 + ni * 16 + l15) * 8]);
      if constexpr (EPI == 2)
        fb2[ni] = *(const half8*)(&Bs2[cur]
            [((size_t)quad * BN + wn * WN * 16 + ni * 16 + l15) * 8]);
    }
    #pragma unroll
    for (int mi = 0; mi < WM; mi++)
      #pragma unroll
      for (int ni = 0; ni < WN; ni++) {
        acc[mi][ni] = mfma16(fa[mi], fb[ni], acc[mi][ni]);
        if constexpr (EPI == 2)
          acc2[mi][ni] = mfma16(fa[mi], fb2[ni], acc2[mi][ni]);
      }
    __syncthreads();
  }

  #pragma unroll
  for (int mi = 0; mi < WM; mi++) {
    const int rbase = m0 + wm * WM * 16 + mi * 16 + quad * 4;
    #pragma unroll
    for (int r = 0; r < 4; r++) {
      const int row = rbase + r;
      if (row >= M) continue;
      #pragma unroll
      for (int ni = 0; ni < WN; ni++) {
        const int col = n0 + wn * WN * 16 + ni * 16 + l15;
        const float v = acc[mi][ni][r];
        if constexpr (EPI == 0) {
          Ch[(size_t)row * ldc + col] = (_Float16)v;
        } else if constexpr (EPI == 1) {
          Cf[(size_t)row * ldc + col] =
              resid[(size_t)row * ldc + col] + v + bias[col];
        } else {
          const float u = v + bias[col];
          const float gg = acc2[mi][ni][r] + bias[col + 2048];
          const float ge = 0.5f * gg * (1.0f + erff(gg * 0.70710678118f));
          Ch[(size_t)row * ldc + col] = (_Float16)(u * ge);
        }
      }
    }
  }
}

// ---------------- flash attention v2, double-buffered ----------------------
__global__ __launch_bounds__(256)
void attn2(const _Float16* __restrict__ Q, const _Float16* __restrict__ K,
           const _Float16* __restrict__ VT, _Float16* __restrict__ O,
           int qStride, int kStride, long kBatchStride,
           int vtStride, int Sk) {
  __shared__ __align__(16) _Float16 KsL[2][2048];
  __shared__ __align__(16) _Float16 VTsL[2][2048];
  __shared__ __align__(16) _Float16 Ps[4][2][16][40];

  const int t = threadIdx.x;
  const int w = t >> 6, lane = t & 63, quad = lane >> 4, l15 = lane & 15;
  const int bh = blockIdx.y, b = bh >> 3, h = bh & 7;
  const int q0 = blockIdx.x * 128 + w * 32;

  const _Float16 qscale = (_Float16)(0.125f * 1.44269504f);
  half8 qf[2][2];
  #pragma unroll
  for (int mi = 0; mi < 2; mi++)
    #pragma unroll
    for (int c = 0; c < 2; c++) {
      const _Float16* qp = Q +
          (size_t)(b * 1024 + q0 + mi * 16 + l15) * qStride +
          h * 64 + c * 32 + quad * 8;
      half8 v = *(const half8*)qp;
      #pragma unroll
      for (int j = 0; j < 8; j++) v[j] *= qscale;
      qf[mi][c] = v;
    }

  f32x4 zero4 = {0.f, 0.f, 0.f, 0.f};
  f32x4 oa[2][4];
  float psum[2][4];
  #pragma unroll
  for (int mi = 0; mi < 2; mi++) {
    #pragma unroll
    for (int nt = 0; nt < 4; nt++) oa[mi][nt] = zero4;
    #pragma unroll
    for (int r = 0; r < 4; r++) psum[mi][r] = 0.f;
  }

  const _Float16* kp = K + (size_t)b * kBatchStride + h * 64;
  const _Float16* vtp = VT + (size_t)bh * 64 * vtStride;
  const int ksk = t & 31, kc = t >> 7, kqd = (t >> 5) & 3;
  const int vd = t & 63, vqd = t >> 6;

  auto stageKV = [&](int skb, int pb) {
    int skc = skb + ksk; if (skc >= Sk) skc = Sk - 1;
    gload16(kp + (size_t)skc * kStride + kc * 32 + kqd * 8, &KsL[pb][t * 8]);
    gload16(vtp + (size_t)vd * vtStride + skb + vqd * 8, &VTsL[pb][t * 8]);
  };

  stageKV(0, 0);
  __syncthreads();

  int it = 0;
  for (int skb = 0; skb < Sk; skb += 32, ++it) {
    const int cur = it & 1;
    if (skb + 32 < Sk) stageKV(skb + 32, cur ^ 1);

    const bool tail = (skb + 32 > Sk);
    #pragma unroll
    for (int mi = 0; mi < 2; mi++) {
      #pragma unroll
      for (int ct = 0; ct < 2; ct++) {
        f32x4 s = zero4;
        half8 kb0 = *(const half8*)(&KsL[cur][(quad * 32 + ct * 16 + l15) * 8]);
        half8 kb1 =
            *(const half8*)(&KsL[cur][(128 + quad * 32 + ct * 16 + l15) * 8]);
        s = mfma16(qf[mi][0], kb0, s);
        s = mfma16(qf[mi][1], kb1, s);
        if (tail) {
          const bool valid = (skb + ct * 16 + l15) < Sk;
          #pragma unroll
          for (int r = 0; r < 4; r++)
            if (!valid) s[r] = -__builtin_inff();
        }
        #pragma unroll
        for (int r = 0; r < 4; r++) {
          const float e = exp2f(s[r]);
          psum[mi][r] += e;
          Ps[w][mi][quad * 4 + r][ct * 16 + l15] = (_Float16)e;
        }
      }
    }
    #pragma unroll
    for (int mi = 0; mi < 2; mi++) {
      const half8 pf = *(const half8*)(&Ps[w][mi][l15][quad * 8]);
      #pragma unroll
      for (int nt = 0; nt < 4; nt++) {
        const half8 vf =
            *(const half8*)(&VTsL[cur][(quad * 64 + nt * 16 + l15) * 8]);
        oa[mi][nt] = mfma16(pf, vf, oa[mi][nt]);
      }
    }
    __syncthreads();
  }

  #pragma unroll
  for (int mi = 0; mi < 2; mi++)
    #pragma unroll
    for (int r = 0; r < 4; r++) {
      #pragma unroll
      for (int mm = 1; mm < 16; mm <<= 1)
        psum[mi][r] += __shfl_xor(psum[mi][r], mm);
      psum[mi][r] = 1.0f / psum[mi][r];
    }

  #pragma unroll
  for (int mi = 0; mi < 2; mi++)
    #pragma unroll
    for (int nt = 0; nt < 4; nt++)
      #pragma unroll
      for (int r = 0; r < 4; r++) {
        const size_t row = (size_t)(b * 1024 + q0 + mi * 16 + quad * 4 + r);
        O[row * 512 + h * 64 + nt * 16 + l15] =
            (_Float16)(oa[mi][nt][r] * psum[mi][r]);
      }
}

// ---------------------------------------------------------------------------
extern "C" void kernel_launch(void* const* d_in, const int* in_sizes, int n_in,
                              void* d_out, int out_size, void* d_ws,
                              size_t ws_size, hipStream_t stream) {
  const float* x    = (const float*)d_in[0];
  const float* enc  = (const float*)d_in[1];
  const float* ln1g = (const float*)d_in[2];
  const float* ln1b = (const float*)d_in[3];
  const float* wq1  = (const float*)d_in[4];
  const float* wk1  = (const float*)d_in[5];
  const float* wv1  = (const float*)d_in[6];
  const float* wo1  = (const float*)d_in[7];
  const float* bo1  = (const float*)d_in[8];
  const float* ln2g = (const float*)d_in[9];
  const float* ln2b = (const float*)d_in[10];
  const float* wq2  = (const float*)d_in[11];
  const float* wk2  = (const float*)d_in[12];
  const float* wv2  = (const float*)d_in[13];
  const float* wo2  = (const float*)d_in[14];
  const float* bo2  = (const float*)d_in[15];
  const float* ln3g = (const float*)d_in[16];
  const float* ln3b = (const float*)d_in[17];
  const float* wg   = (const float*)d_in[18];
  const float* bg   = (const float*)d_in[19];
  const float* wf   = (const float*)d_in[20];
  const float* bfp  = (const float*)d_in[21];
  float* out = (float*)d_out;

  char* ws = (char*)d_ws;
  _Float16* qkvT  = (_Float16*)(ws + 0);         // [1536,512]
  _Float16* q2T   = (_Float16*)(ws + 1572864);   // [512,512]
  _Float16* kv2T  = (_Float16*)(ws + 2097152);   // [1024,768]
  _Float16* wo1T  = (_Float16*)(ws + 3670016);   // [512,512]
  _Float16* wo2T  = (_Float16*)(ws + 4194304);   // [512,512]
  _Float16* wgT   = (_Float16*)(ws + 4718592);   // [4096,512]
  _Float16* wfT   = (_Float16*)(ws + 8912896);   // [512,2048]
  _Float16* hbuf  = (_Float16*)(ws + 11010048);  // [8192,512] (VTself in attn1)
  _Float16* qkv   = (_Float16*)(ws + 19398656);  // [8192,1536]
  _Float16* q2b   = (_Float16*)(ws + 44564480);  // [8192,512]
  _Float16* kv2b  = (_Float16*)(ws + 52953088);  // [616,1024]
  _Float16* attnb = (_Float16*)(ws + 54214656);  // [8192,512]
  _Float16* ench  = (_Float16*)(ws + 62603264);  // [616,768]
  _Float16* ffb   = (_Float16*)(ws + 19398656);  // [8192,2048] aliases qkv+q2b
  _Float16* VTself = hbuf;                       // [4096,1024]
  _Float16* VTc   = (_Float16*)(ws + 62603264);  // [4096,96] over ench (dead
                                                 // after kv2 GEMM)

  // ---- fused prep: weights + enc + LN1 (one launch) ----
  PrepArgs pa;
  const float* srcs[10] = {wq1, wk1, wv1, wo1, wq2, wk2, wv2, wo2, wg, wf};
  _Float16* dsts[10] = {qkvT, qkvT + 512 * 512, qkvT + 1024 * 512, wo1T, q2T,
                        kv2T, kv2T + 512 * 768, wo2T, wgT, wfT};
  const int Ks[10] = {512, 512, 512, 512, 512, 768, 768, 512, 512, 2048};
  const int Ns[10] = {512, 512, 512, 512, 512, 512, 512, 512, 4096, 512};
  int base = 0;
  for (int i = 0; i < 10; i++) {
    pa.src[i] = srcs[i]; pa.dst[i] = dsts[i];
    pa.K[i] = Ks[i]; pa.N[i] = Ns[i]; pa.base[i] = base;
    base += (Ks[i] >> 5) * (Ns[i] >> 5);
  }
  pa.enc = enc; pa.ench = ench; pa.encBase = base; pa.nEnc = 473088;
  base += (473088 + 255) / 256;
  pa.x = x; pa.ln1g = ln1g; pa.ln1b = ln1b; pa.hbuf = hbuf; pa.lnBase = base;
  base += 8192;
  prep_all<<<base, dim3(32, 8), 0, stream>>>(pa);

  const dim3 tb(32, 8);

  // ---- self-attention block ----
  gemm_bt<0, 2, 2, 4, 4, 3, 1><<<768, 256, 0, stream>>>(
      hbuf, qkvT, 8192, 1536, 512, 512, 1536, qkv, nullptr, nullptr, nullptr);
  vt_kernel<<<dim3(32, 2, 64), tb, 0, stream>>>(qkv + 1024, VTself, 1024,
                                                1536, 1024);
  attn2<<<dim3(8, 64), 256, 0, stream>>>(qkv, qkv + 512, VTself, attnb,
                                         1536, 1536, (long)1024 * 1536,
                                         1024, 1024);
  gemm_bt<1, 1, 4, 4, 2, 3, 1><<<512, 256, 0, stream>>>(
      attnb, wo1T, 8192, 512, 512, 512, 512, nullptr, out, bo1, x);

  // ---- cross-attention block ----
  ln_kernel<<<8192, 256, 0, stream>>>(out, ln2g, ln2b, hbuf);
  gemm_bt<0, 1, 4, 4, 2, 3, 1><<<512, 256, 0, stream>>>(
      hbuf, q2T, 8192, 512, 512, 512, 512, q2b, nullptr, nullptr, nullptr);
  gemm_bt<0, 1, 4, 4, 2, 3, 0><<<80, 256, 0, stream>>>(
      ench, kv2T, 616, 1024, 768, 768, 1024, kv2b, nullptr, nullptr, nullptr);
  vt_kernel<<<dim3(3, 2, 64), tb, 0, stream>>>(kv2b + 512, VTc, 77, 1024, 96);
  attn2<<<dim3(8, 64), 256, 0, stream>>>(q2b, kv2b, VTc, attnb,
                                         512, 1024, (long)77 * 1024, 96, 77);
  gemm_bt<1, 1, 4, 4, 2, 3, 1><<<512, 256, 0, stream>>>(
      attnb, wo2T, 8192, 512, 512, 512, 512, nullptr, out, bo2, out);

  // ---- GEGLU feed-forward ----
  ln_kernel<<<8192, 256, 0, stream>>>(out, ln3g, ln3b, hbuf);
  gemm_bt<2, 2, 2, 4, 2, 4, 1><<<2048, 256, 0, stream>>>(
      hbuf, wgT, 8192, 2048, 512, 512, 2048, ffb, nullptr, bg, nullptr);
  gemm_bt<1, 1, 4, 4, 2, 3, 1><<<512, 256, 0, stream>>>(
      ffb, wfT, 8192, 512, 2048, 2048, 512, nullptr, out, bfp, out);
}